// Round 1
// 574.521 us; speedup vs baseline: 1.0137x; 1.0137x over previous
//
#include <hip/hip_runtime.h>
#include <math.h>

// Problem constants (fixed by the reference)
#define T_CNT 4
#define U_DIM 10
#define A_DIM 20
#define EMB_D 200
#define N_SRC 65536
#define N_DST 8192
#define E_PER_T 262144

#define NCHUNK 8                  // dst chunks
#define DCHUNK (N_DST / NCHUNK)   // 1024 dsts per chunk -> 40 KB LDS acc

// Padded src_feat layout: [N_SRC][T][12] floats; each (node,t) slice is
// 48 B-aligned so scan can gather with float4+float4+float2 (3 loads, not 5).
#define SF_TSTRIDE 12
#define SF_STRIDE (T_CNT * SF_TSTRIDE)   // 48 floats per src row

// NSEG 32 -> 8: part shrinks 41.9 MB -> 10.5 MB (L2/L3-resident for the
// finalize reduce); scan blocks widen to 1024 threads so total wave count
// and per-CU occupancy (16 waves/CU) are unchanged.
#define NSEG_MAIN 8
#define ESEG_MAIN (E_PER_T / NSEG_MAIN)   // 32768

// ---------------------------------------------------------------------------
// Kernel 1: gather node_type_embeddings[input_nodes] -> padded src_feat.
// One thread per (src, t) slice: read 5 float2 (40 B, only 8B-aligned in the
// source table), write float4/float4/float2 into the 16B-aligned padded row.
__global__ __launch_bounds__(256)
void gather_kernel(const int* __restrict__ input_nodes,
                   const float2* __restrict__ nte2,   // node_type_emb as float2
                   float* __restrict__ sf) {          // [N_SRC][T][12]
    int id = blockIdx.x * 256 + threadIdx.x;          // [0, N_SRC*T)
    if (id >= N_SRC * T_CNT) return;
    int i = id >> 2;
    int t = id & 3;
    int node = input_nodes[i];
    const float2* src = nte2 + ((size_t)node * (T_CNT * U_DIM) + t * U_DIM) / 2;
    float2 v0 = src[0], v1 = src[1], v2 = src[2], v3 = src[3], v4 = src[4];
    float* dst = sf + (size_t)id * SF_TSTRIDE;
    *reinterpret_cast<float4*>(dst)     = make_float4(v0.x, v0.y, v1.x, v1.y);
    *reinterpret_cast<float4*>(dst + 4) = make_float4(v2.x, v2.y, v3.x, v3.y);
    *reinterpret_cast<float2*>(dst + 8) = v4;
}

// ---------------------------------------------------------------------------
// Kernel 2: chunk-scan aggregation (no global atomics).
// Block (s, t, c): 1024 threads scan edge segment s of type t; edges whose
// dst lands in chunk c accumulate into 40 KB LDS; block then writes its
// exclusive partial slice with plain stores.
// ESEG is compile-time: the iter loop fully unrolls; next-quad edge loads are
// issued before the current quad's gathers are consumed.
template <int ESEG>
__global__ __launch_bounds__(1024)
void scan_kernel(const int* __restrict__ edge_src,
                 const int* __restrict__ edge_dst,
                 const float* __restrict__ src_feat,  // [N_SRC][T][12]
                 float* __restrict__ part) {          // [nseg, T, N_DST, U]
    __shared__ float acc[DCHUNK * U_DIM];             // 10240 floats = 40 KB

    const int b = blockIdx.x;
    const int c = b & (NCHUNK - 1);
    const int t = (b >> 3) & (T_CNT - 1);
    const int s = b >> 5;
    const int base = c * DCHUNK;

    for (int i = threadIdx.x; i < DCHUNK * U_DIM; i += 1024) acc[i] = 0.f;
    __syncthreads();

    const int* ed = edge_dst + (size_t)t * E_PER_T + (size_t)s * ESEG;
    const int* es = edge_src + (size_t)t * E_PER_T + (size_t)s * ESEG;

    constexpr int ITERS = ESEG / 4096;   // 1024 threads x 4 edges per iter
    int k = threadIdx.x * 4;
    int4 d_cur = *reinterpret_cast<const int4*>(ed + k);
    int4 s_cur = *reinterpret_cast<const int4*>(es + k);

#pragma unroll
    for (int it = 0; it < ITERS; ++it) {
        int4 d_nxt = make_int4(0, 0, 0, 0), s_nxt = make_int4(0, 0, 0, 0);
        if (it + 1 < ITERS) {   // compile-time branch
            d_nxt = *reinterpret_cast<const int4*>(ed + k + 4096);
            s_nxt = *reinterpret_cast<const int4*>(es + k + 4096);
        }
        int dsts[4] = {d_cur.x, d_cur.y, d_cur.z, d_cur.w};
        int srcs[4] = {s_cur.x, s_cur.y, s_cur.z, s_cur.w};
        unsigned r[4];
        bool p[4];
#pragma unroll
        for (int j = 0; j < 4; ++j) {
            r[j] = (unsigned)(dsts[j] - base);
            p[j] = r[j] < DCHUNK;
        }
        // Phase 1: issue ALL gathers (batched -> one waitcnt chain)
        float4 va[4], vb[4];
        float2 vc[4];
#pragma unroll
        for (int j = 0; j < 4; ++j) {
            if (p[j]) {
                const float* fp = src_feat + (size_t)srcs[j] * SF_STRIDE + t * SF_TSTRIDE;
                va[j] = *reinterpret_cast<const float4*>(fp);
                vb[j] = *reinterpret_cast<const float4*>(fp + 4);
                vc[j] = *reinterpret_cast<const float2*>(fp + 8);
            }
        }
        // Phase 2: consume into LDS
#pragma unroll
        for (int j = 0; j < 4; ++j) {
            if (p[j]) {
                float* a = acc + (int)r[j] * U_DIM;
                atomicAdd(a + 0, va[j].x);
                atomicAdd(a + 1, va[j].y);
                atomicAdd(a + 2, va[j].z);
                atomicAdd(a + 3, va[j].w);
                atomicAdd(a + 4, vb[j].x);
                atomicAdd(a + 5, vb[j].y);
                atomicAdd(a + 6, vb[j].z);
                atomicAdd(a + 7, vb[j].w);
                atomicAdd(a + 8, vc[j].x);
                atomicAdd(a + 9, vc[j].y);
            }
        }
        d_cur = d_nxt;
        s_cur = s_nxt;
        k += 4096;
    }
    __syncthreads();

    float* outp = part + (((size_t)(s * T_CNT + t)) * N_DST + base) * U_DIM;
    for (int i = threadIdx.x; i < DCHUNK * U_DIM; i += 1024) outp[i] = acc[i];
}

// Generic fallback (runtime eseg, 256 threads) — only if ws_size is tiny.
__global__ __launch_bounds__(256)
void scan_kernel_gen(const int* __restrict__ edge_src,
                     const int* __restrict__ edge_dst,
                     const float* __restrict__ src_feat,  // padded layout
                     float* __restrict__ part, int eseg) {
    __shared__ float acc[DCHUNK * U_DIM];
    const int b = blockIdx.x;
    const int c = b & (NCHUNK - 1);
    const int t = (b >> 3) & (T_CNT - 1);
    const int s = b >> 5;
    const int base = c * DCHUNK;
    for (int i = threadIdx.x; i < DCHUNK * U_DIM; i += 256) acc[i] = 0.f;
    __syncthreads();
    const int* ed = edge_dst + (size_t)t * E_PER_T + (size_t)s * eseg;
    const int* es = edge_src + (size_t)t * E_PER_T + (size_t)s * eseg;
    for (int k = threadIdx.x * 4; k < eseg; k += 1024) {
        int4 d4 = *reinterpret_cast<const int4*>(ed + k);
        int4 s4 = *reinterpret_cast<const int4*>(es + k);
        int dsts[4] = {d4.x, d4.y, d4.z, d4.w};
        int srcs[4] = {s4.x, s4.y, s4.z, s4.w};
#pragma unroll
        for (int j = 0; j < 4; ++j) {
            unsigned r = (unsigned)(dsts[j] - base);
            if (r < DCHUNK) {
                const float* fp = src_feat + (size_t)srcs[j] * SF_STRIDE + t * SF_TSTRIDE;
                float4 va = *reinterpret_cast<const float4*>(fp);
                float4 vb = *reinterpret_cast<const float4*>(fp + 4);
                float2 vc = *reinterpret_cast<const float2*>(fp + 8);
                float* a = acc + (int)r * U_DIM;
                atomicAdd(a + 0, va.x); atomicAdd(a + 1, va.y);
                atomicAdd(a + 2, va.z); atomicAdd(a + 3, va.w);
                atomicAdd(a + 4, vb.x); atomicAdd(a + 5, vb.y);
                atomicAdd(a + 6, vb.z); atomicAdd(a + 7, vb.w);
                atomicAdd(a + 8, vc.x); atomicAdd(a + 9, vc.y);
            }
        }
    }
    __syncthreads();
    float* outp = part + (((size_t)(s * T_CNT + t)) * N_DST + base) * U_DIM;
    for (int i = threadIdx.x; i < DCHUNK * U_DIM; i += 256) outp[i] = acc[i];
}

// ---------------------------------------------------------------------------
// Kernel 3: per-dst-node attention + projection + L2 normalize.
// NSEG compile-time -> the partial reduction fully unrolls into NSEG
// independent loads (single waitcnt).
template <int NSEG>
__global__ __launch_bounds__(256)
void finalize_kernel(const float* __restrict__ part,       // [NSEG,T,N_DST,U]
                     const int* __restrict__ output_nodes, // [N_DST]
                     const float* __restrict__ node_emb,   // [NUM_NODES,200]
                     const float* __restrict__ W,          // [T,U,EMB]
                     const float* __restrict__ S1,         // [T,U,A]
                     const float* __restrict__ S2,         // [T,A]
                     float* __restrict__ out) {            // [N_DST,T,EMB]
    const int b = blockIdx.x;
    const int tid = threadIdx.x;

    __shared__ float sNte[T_CNT * U_DIM];   // 40
    __shared__ float sH[T_CNT * A_DIM];     // 80
    __shared__ float sScore[T_CNT];
    __shared__ float sAtt[T_CNT];
    __shared__ float sComb[U_DIM];
    __shared__ float sBase[EMB_D];

    if (tid < T_CNT * U_DIM) {
        const float* p = part + (size_t)b * U_DIM +
                         ((size_t)(tid / U_DIM) * N_DST) * U_DIM + (tid % U_DIM);
        float v[NSEG];
#pragma unroll
        for (int s = 0; s < NSEG; ++s)
            v[s] = p[(size_t)s * (T_CNT * N_DST * U_DIM)];
        float sum = 0.f;
#pragma unroll
        for (int s = 0; s < NSEG; ++s) sum += v[s];
        sNte[tid] = sum;
    }
    const int on = output_nodes[b];
    if (tid < EMB_D) sBase[tid] = node_emb[(size_t)on * EMB_D + tid];
    __syncthreads();

    // h[t][a] = tanh(sum_u nte[t][u] * S1[t][u][a])
    if (tid < T_CNT * A_DIM) {
        int t = tid / A_DIM, a = tid - t * A_DIM;
        float s = 0.f;
#pragma unroll
        for (int u = 0; u < U_DIM; ++u)
            s += sNte[t * U_DIM + u] * S1[t * (U_DIM * A_DIM) + u * A_DIM + a];
        sH[tid] = tanhf(s);
    }
    __syncthreads();

    // scores[t] = sum_a h[t][a] * S2[t][a]
    if (tid < T_CNT) {
        float s = 0.f;
#pragma unroll
        for (int a = 0; a < A_DIM; ++a)
            s += sH[tid * A_DIM + a] * S2[tid * A_DIM + a];
        sScore[tid] = s;
    }
    __syncthreads();

    // softmax over T (tiny, single thread)
    if (tid == 0) {
        float m = sScore[0];
#pragma unroll
        for (int t = 1; t < T_CNT; ++t) m = fmaxf(m, sScore[t]);
        float sum = 0.f;
#pragma unroll
        for (int t = 0; t < T_CNT; ++t) {
            float e = __expf(sScore[t] - m);
            sAtt[t] = e;
            sum += e;
        }
        float inv = 1.f / sum;
#pragma unroll
        for (int t = 0; t < T_CNT; ++t) sAtt[t] *= inv;
    }
    __syncthreads();

    // combined[u] = sum_t att[t] * nte[t][u]
    if (tid < U_DIM) {
        float s = 0.f;
#pragma unroll
        for (int t = 0; t < T_CNT; ++t) s += sAtt[t] * sNte[t * U_DIM + tid];
        sComb[tid] = s;
    }
    __syncthreads();

    // wave w = t: out[b][t][e] = normalize(base[e] + sum_u comb[u]*W[t][u][e])
    const int t = tid >> 6;
    const int lane = tid & 63;
    float c[U_DIM];
#pragma unroll
    for (int u = 0; u < U_DIM; ++u) c[u] = sComb[u];

    float v[4];
    float sq = 0.f;
#pragma unroll
    for (int j = 0; j < 4; ++j) {
        int e = lane + j * 64;
        if (e < EMB_D) {
            float s = sBase[e];
            const float* w = W + t * (U_DIM * EMB_D) + e;
#pragma unroll
            for (int u = 0; u < U_DIM; ++u) s += c[u] * w[u * EMB_D];
            v[j] = s;
            sq += s * s;
        }
    }
#pragma unroll
    for (int off = 32; off > 0; off >>= 1) sq += __shfl_xor(sq, off);

    float n = sqrtf(sq);
    float inv = 1.f / fmaxf(n, 1e-12f);

    float* o = out + (size_t)b * (T_CNT * EMB_D) + t * EMB_D;
#pragma unroll
    for (int j = 0; j < 4; ++j) {
        int e = lane + j * 64;
        if (e < EMB_D) o[e] = v[j] * inv;
    }
}

// ---------------------------------------------------------------------------
extern "C" void kernel_launch(void* const* d_in, const int* in_sizes, int n_in,
                              void* d_out, int out_size, void* d_ws, size_t ws_size,
                              hipStream_t stream) {
    const int*   input_nodes   = (const int*)d_in[0];
    const int*   output_nodes  = (const int*)d_in[1];
    const int*   edge_src      = (const int*)d_in[2];
    const int*   edge_dst      = (const int*)d_in[3];
    const float* node_emb      = (const float*)d_in[4];
    const float* node_type_emb = (const float*)d_in[5];
    const float* W             = (const float*)d_in[6];
    const float* S1            = (const float*)d_in[7];
    const float* S2            = (const float*)d_in[8];
    float*       out           = (float*)d_out;

    // Workspace layout: [src_feat 12.6 MB padded][part nseg * 1.31 MB]
    const size_t gatherBytes = (size_t)N_SRC * SF_STRIDE * sizeof(float);
    const size_t segBytes = (size_t)T_CNT * N_DST * U_DIM * sizeof(float);
    const size_t needMain = gatherBytes + NSEG_MAIN * segBytes;   // ~23 MB

    float* src_feat = (float*)d_ws;

    const int nGather = N_SRC * T_CNT;   // one thread per (src, t) slice

    if (ws_size >= needMain) {
        // Main path (always taken: ws_size is ~1.6 GB): nseg=8, eseg=32768,
        // 1024-thread scan blocks (grid 256 = 1 block/CU, 16 waves/CU).
        float* part = (float*)((char*)d_ws + gatherBytes);
        gather_kernel<<<(nGather + 255) / 256, 256, 0, stream>>>(
            input_nodes, (const float2*)node_type_emb, src_feat);
        scan_kernel<ESEG_MAIN><<<NCHUNK * T_CNT * NSEG_MAIN, 1024, 0, stream>>>(
            edge_src, edge_dst, src_feat, part);
        finalize_kernel<NSEG_MAIN><<<N_DST, 256, 0, stream>>>(
            part, output_nodes, node_emb, W, S1, S2, out);
    } else {
        // Fallback: smaller nseg, runtime loop bounds (requires pre-gather fit).
        size_t avail = (ws_size > gatherBytes) ? (ws_size - gatherBytes) : 0;
        int nseg = (int)(avail / segBytes);
        if (nseg > 32) nseg = 32;
        if (nseg < 1) nseg = 1;
        while (nseg & (nseg - 1)) nseg--;
        const int eseg = E_PER_T / nseg;
        float* part = (float*)((char*)d_ws + gatherBytes);
        gather_kernel<<<(nGather + 255) / 256, 256, 0, stream>>>(
            input_nodes, (const float2*)node_type_emb, src_feat);
        scan_kernel_gen<<<NCHUNK * T_CNT * nseg, 256, 0, stream>>>(
            edge_src, edge_dst, src_feat, part, eseg);
        switch (nseg) {
            case 32: finalize_kernel<32><<<N_DST, 256, 0, stream>>>(part, output_nodes, node_emb, W, S1, S2, out); break;
            case 16: finalize_kernel<16><<<N_DST, 256, 0, stream>>>(part, output_nodes, node_emb, W, S1, S2, out); break;
            case 8:  finalize_kernel<8><<<N_DST, 256, 0, stream>>>(part, output_nodes, node_emb, W, S1, S2, out); break;
            case 4:  finalize_kernel<4><<<N_DST, 256, 0, stream>>>(part, output_nodes, node_emb, W, S1, S2, out); break;
            case 2:  finalize_kernel<2><<<N_DST, 256, 0, stream>>>(part, output_nodes, node_emb, W, S1, S2, out); break;
            default: finalize_kernel<1><<<N_DST, 256, 0, stream>>>(part, output_nodes, node_emb, W, S1, S2, out); break;
        }
    }
}

// Round 2
// 573.276 us; speedup vs baseline: 1.0159x; 1.0022x over previous
//
#include <hip/hip_runtime.h>
#include <math.h>

// Problem constants (fixed by the reference)
#define T_CNT 4
#define U_DIM 10
#define A_DIM 20
#define EMB_D 200
#define N_SRC 65536
#define N_DST 8192
#define E_PER_T 262144

#define NCHUNK 8                  // dst chunks
#define DCHUNK (N_DST / NCHUNK)   // 1024 dsts per chunk -> 40 KB LDS acc

// src_feat layout: per-type slabs [T][N_SRC][12] floats. Each slab is
// 3.07 MB -> fits one XCD's 4 MB L2. Rows padded to 12 floats so each
// (t, src) slice is 16B-aligned (float4+float4+float2 gather: 3 loads).
#define SF_TSTRIDE 12
#define SF_SLAB ((size_t)N_SRC * SF_TSTRIDE)   // floats per type slab

#define NSEG_MAIN 8
#define ESEG_MAIN (E_PER_T / NSEG_MAIN)   // 32768

// ---------------------------------------------------------------------------
// Kernel 1: gather node_type_embeddings[input_nodes] -> per-type slabs.
// Thread id = i*4+t: the 4 threads sharing a node row read adjacent 40 B
// slices (line reuse in L1); writes go to 4 slab regions, each wave writing
// 16 consecutive 48 B rows per slab (acceptable coalescing).
__global__ __launch_bounds__(256)
void gather_kernel(const int* __restrict__ input_nodes,
                   const float2* __restrict__ nte2,   // node_type_emb as float2
                   float* __restrict__ sf) {          // [T][N_SRC][12]
    int id = blockIdx.x * 256 + threadIdx.x;          // [0, N_SRC*T)
    if (id >= N_SRC * T_CNT) return;
    int i = id >> 2;
    int t = id & 3;
    int node = input_nodes[i];
    const float2* src = nte2 + (size_t)node * (T_CNT * U_DIM / 2) + t * (U_DIM / 2);
    float2 v0 = src[0], v1 = src[1], v2 = src[2], v3 = src[3], v4 = src[4];
    float* dst = sf + (size_t)t * SF_SLAB + (size_t)i * SF_TSTRIDE;
    *reinterpret_cast<float4*>(dst)     = make_float4(v0.x, v0.y, v1.x, v1.y);
    *reinterpret_cast<float4*>(dst + 4) = make_float4(v2.x, v2.y, v3.x, v3.y);
    *reinterpret_cast<float2*>(dst + 8) = v4;
}

// ---------------------------------------------------------------------------
// Kernel 2: chunk-scan aggregation (no global atomics).
// Block (s, t, c): 1024 threads scan edge segment s of type t; edges whose
// dst lands in chunk c accumulate into 40 KB LDS; block then writes its
// exclusive partial slice with plain stores.
//
// XCD-aware block remap (bijective): under the round-robin dispatch
// heuristic (xcd = blockIdx % 8), each pair of XCDs serves exactly ONE edge
// type -> per-XCD gather footprint = one 3.07 MB type slab + ~2 MB of that
// type's edge lists, fully L2-resident. If the heuristic is wrong this is
// still a bijection: correctness unaffected.
template <int ESEG>
__global__ __launch_bounds__(1024)
void scan_kernel(const int* __restrict__ edge_src,
                 const int* __restrict__ edge_dst,
                 const float* __restrict__ src_feat,  // [T][N_SRC][12]
                 float* __restrict__ part) {          // [nseg, T, N_DST, U]
    __shared__ float acc[DCHUNK * U_DIM];             // 10240 floats = 40 KB

    const int x = blockIdx.x;                 // 0..255
    const int xcd = x & 7;
    const int widx = x >> 3;                  // 0..31 within-XCD index
    const int t = xcd >> 1;                   // 2 XCDs per type
    const int pair = ((xcd & 1) << 5) | widx; // 0..63 -> (s, c)
    const int c = pair & (NCHUNK - 1);
    const int s = pair >> 3;                  // 0..7 (NSEG_MAIN == 8)
    const int base = c * DCHUNK;

    for (int i = threadIdx.x; i < DCHUNK * U_DIM; i += 1024) acc[i] = 0.f;
    __syncthreads();

    const int* ed = edge_dst + (size_t)t * E_PER_T + (size_t)s * ESEG;
    const int* es = edge_src + (size_t)t * E_PER_T + (size_t)s * ESEG;
    const float* sft = src_feat + (size_t)t * SF_SLAB;

    constexpr int ITERS = ESEG / 4096;   // 1024 threads x 4 edges per iter
    int k = threadIdx.x * 4;
    int4 d_cur = *reinterpret_cast<const int4*>(ed + k);
    int4 s_cur = *reinterpret_cast<const int4*>(es + k);

#pragma unroll
    for (int it = 0; it < ITERS; ++it) {
        int4 d_nxt = make_int4(0, 0, 0, 0), s_nxt = make_int4(0, 0, 0, 0);
        if (it + 1 < ITERS) {   // compile-time branch
            d_nxt = *reinterpret_cast<const int4*>(ed + k + 4096);
            s_nxt = *reinterpret_cast<const int4*>(es + k + 4096);
        }
        int dsts[4] = {d_cur.x, d_cur.y, d_cur.z, d_cur.w};
        int srcs[4] = {s_cur.x, s_cur.y, s_cur.z, s_cur.w};
        unsigned r[4];
        bool p[4];
#pragma unroll
        for (int j = 0; j < 4; ++j) {
            r[j] = (unsigned)(dsts[j] - base);
            p[j] = r[j] < DCHUNK;
        }
        // Phase 1: issue ALL gathers (batched -> one waitcnt chain)
        float4 va[4], vb[4];
        float2 vc[4];
#pragma unroll
        for (int j = 0; j < 4; ++j) {
            if (p[j]) {
                const float* fp = sft + (size_t)srcs[j] * SF_TSTRIDE;
                va[j] = *reinterpret_cast<const float4*>(fp);
                vb[j] = *reinterpret_cast<const float4*>(fp + 4);
                vc[j] = *reinterpret_cast<const float2*>(fp + 8);
            }
        }
        // Phase 2: consume into LDS
#pragma unroll
        for (int j = 0; j < 4; ++j) {
            if (p[j]) {
                float* a = acc + (int)r[j] * U_DIM;
                atomicAdd(a + 0, va[j].x);
                atomicAdd(a + 1, va[j].y);
                atomicAdd(a + 2, va[j].z);
                atomicAdd(a + 3, va[j].w);
                atomicAdd(a + 4, vb[j].x);
                atomicAdd(a + 5, vb[j].y);
                atomicAdd(a + 6, vb[j].z);
                atomicAdd(a + 7, vb[j].w);
                atomicAdd(a + 8, vc[j].x);
                atomicAdd(a + 9, vc[j].y);
            }
        }
        d_cur = d_nxt;
        s_cur = s_nxt;
        k += 4096;
    }
    __syncthreads();

    float* outp = part + (((size_t)(s * T_CNT + t)) * N_DST + base) * U_DIM;
    for (int i = threadIdx.x; i < DCHUNK * U_DIM; i += 1024) outp[i] = acc[i];
}

// Generic fallback (runtime eseg, 256 threads) — only if ws_size is tiny.
__global__ __launch_bounds__(256)
void scan_kernel_gen(const int* __restrict__ edge_src,
                     const int* __restrict__ edge_dst,
                     const float* __restrict__ src_feat,  // slab layout
                     float* __restrict__ part, int eseg) {
    __shared__ float acc[DCHUNK * U_DIM];
    const int b = blockIdx.x;
    const int c = b & (NCHUNK - 1);
    const int t = (b >> 3) & (T_CNT - 1);
    const int s = b >> 5;
    const int base = c * DCHUNK;
    for (int i = threadIdx.x; i < DCHUNK * U_DIM; i += 256) acc[i] = 0.f;
    __syncthreads();
    const int* ed = edge_dst + (size_t)t * E_PER_T + (size_t)s * eseg;
    const int* es = edge_src + (size_t)t * E_PER_T + (size_t)s * eseg;
    const float* sft = src_feat + (size_t)t * SF_SLAB;
    for (int k = threadIdx.x * 4; k < eseg; k += 1024) {
        int4 d4 = *reinterpret_cast<const int4*>(ed + k);
        int4 s4 = *reinterpret_cast<const int4*>(es + k);
        int dsts[4] = {d4.x, d4.y, d4.z, d4.w};
        int srcs[4] = {s4.x, s4.y, s4.z, s4.w};
#pragma unroll
        for (int j = 0; j < 4; ++j) {
            unsigned r = (unsigned)(dsts[j] - base);
            if (r < DCHUNK) {
                const float* fp = sft + (size_t)srcs[j] * SF_TSTRIDE;
                float4 va = *reinterpret_cast<const float4*>(fp);
                float4 vb = *reinterpret_cast<const float4*>(fp + 4);
                float2 vc = *reinterpret_cast<const float2*>(fp + 8);
                float* a = acc + (int)r * U_DIM;
                atomicAdd(a + 0, va.x); atomicAdd(a + 1, va.y);
                atomicAdd(a + 2, va.z); atomicAdd(a + 3, va.w);
                atomicAdd(a + 4, vb.x); atomicAdd(a + 5, vb.y);
                atomicAdd(a + 6, vb.z); atomicAdd(a + 7, vb.w);
                atomicAdd(a + 8, vc.x); atomicAdd(a + 9, vc.y);
            }
        }
    }
    __syncthreads();
    float* outp = part + (((size_t)(s * T_CNT + t)) * N_DST + base) * U_DIM;
    for (int i = threadIdx.x; i < DCHUNK * U_DIM; i += 256) outp[i] = acc[i];
}

// ---------------------------------------------------------------------------
// Kernel 3: per-dst-node attention + projection + L2 normalize.
// NSEG compile-time -> the partial reduction fully unrolls into NSEG
// independent loads (single waitcnt).
template <int NSEG>
__global__ __launch_bounds__(256)
void finalize_kernel(const float* __restrict__ part,       // [NSEG,T,N_DST,U]
                     const int* __restrict__ output_nodes, // [N_DST]
                     const float* __restrict__ node_emb,   // [NUM_NODES,200]
                     const float* __restrict__ W,          // [T,U,EMB]
                     const float* __restrict__ S1,         // [T,U,A]
                     const float* __restrict__ S2,         // [T,A]
                     float* __restrict__ out) {            // [N_DST,T,EMB]
    const int b = blockIdx.x;
    const int tid = threadIdx.x;

    __shared__ float sNte[T_CNT * U_DIM];   // 40
    __shared__ float sH[T_CNT * A_DIM];     // 80
    __shared__ float sScore[T_CNT];
    __shared__ float sAtt[T_CNT];
    __shared__ float sComb[U_DIM];
    __shared__ float sBase[EMB_D];

    if (tid < T_CNT * U_DIM) {
        const float* p = part + (size_t)b * U_DIM +
                         ((size_t)(tid / U_DIM) * N_DST) * U_DIM + (tid % U_DIM);
        float v[NSEG];
#pragma unroll
        for (int s = 0; s < NSEG; ++s)
            v[s] = p[(size_t)s * (T_CNT * N_DST * U_DIM)];
        float sum = 0.f;
#pragma unroll
        for (int s = 0; s < NSEG; ++s) sum += v[s];
        sNte[tid] = sum;
    }
    const int on = output_nodes[b];
    if (tid < EMB_D) sBase[tid] = node_emb[(size_t)on * EMB_D + tid];
    __syncthreads();

    // h[t][a] = tanh(sum_u nte[t][u] * S1[t][u][a])
    if (tid < T_CNT * A_DIM) {
        int t = tid / A_DIM, a = tid - t * A_DIM;
        float s = 0.f;
#pragma unroll
        for (int u = 0; u < U_DIM; ++u)
            s += sNte[t * U_DIM + u] * S1[t * (U_DIM * A_DIM) + u * A_DIM + a];
        sH[tid] = tanhf(s);
    }
    __syncthreads();

    // scores[t] = sum_a h[t][a] * S2[t][a]
    if (tid < T_CNT) {
        float s = 0.f;
#pragma unroll
        for (int a = 0; a < A_DIM; ++a)
            s += sH[tid * A_DIM + a] * S2[tid * A_DIM + a];
        sScore[tid] = s;
    }
    __syncthreads();

    // softmax over T (tiny, single thread)
    if (tid == 0) {
        float m = sScore[0];
#pragma unroll
        for (int t = 1; t < T_CNT; ++t) m = fmaxf(m, sScore[t]);
        float sum = 0.f;
#pragma unroll
        for (int t = 0; t < T_CNT; ++t) {
            float e = __expf(sScore[t] - m);
            sAtt[t] = e;
            sum += e;
        }
        float inv = 1.f / sum;
#pragma unroll
        for (int t = 0; t < T_CNT; ++t) sAtt[t] *= inv;
    }
    __syncthreads();

    // combined[u] = sum_t att[t] * nte[t][u]
    if (tid < U_DIM) {
        float s = 0.f;
#pragma unroll
        for (int t = 0; t < T_CNT; ++t) s += sAtt[t] * sNte[t * U_DIM + tid];
        sComb[tid] = s;
    }
    __syncthreads();

    // wave w = t: out[b][t][e] = normalize(base[e] + sum_u comb[u]*W[t][u][e])
    const int t = tid >> 6;
    const int lane = tid & 63;
    float c[U_DIM];
#pragma unroll
    for (int u = 0; u < U_DIM; ++u) c[u] = sComb[u];

    float v[4];
    float sq = 0.f;
#pragma unroll
    for (int j = 0; j < 4; ++j) {
        int e = lane + j * 64;
        if (e < EMB_D) {
            float s = sBase[e];
            const float* w = W + t * (U_DIM * EMB_D) + e;
#pragma unroll
            for (int u = 0; u < U_DIM; ++u) s += c[u] * w[u * EMB_D];
            v[j] = s;
            sq += s * s;
        }
    }
#pragma unroll
    for (int off = 32; off > 0; off >>= 1) sq += __shfl_xor(sq, off);

    float n = sqrtf(sq);
    float inv = 1.f / fmaxf(n, 1e-12f);

    float* o = out + (size_t)b * (T_CNT * EMB_D) + t * EMB_D;
#pragma unroll
    for (int j = 0; j < 4; ++j) {
        int e = lane + j * 64;
        if (e < EMB_D) o[e] = v[j] * inv;
    }
}

// ---------------------------------------------------------------------------
extern "C" void kernel_launch(void* const* d_in, const int* in_sizes, int n_in,
                              void* d_out, int out_size, void* d_ws, size_t ws_size,
                              hipStream_t stream) {
    const int*   input_nodes   = (const int*)d_in[0];
    const int*   output_nodes  = (const int*)d_in[1];
    const int*   edge_src      = (const int*)d_in[2];
    const int*   edge_dst      = (const int*)d_in[3];
    const float* node_emb      = (const float*)d_in[4];
    const float* node_type_emb = (const float*)d_in[5];
    const float* W             = (const float*)d_in[6];
    const float* S1            = (const float*)d_in[7];
    const float* S2            = (const float*)d_in[8];
    float*       out           = (float*)d_out;

    // Workspace layout: [src_feat slabs 12.6 MB][part nseg * 1.31 MB]
    const size_t gatherBytes = (size_t)T_CNT * SF_SLAB * sizeof(float);
    const size_t segBytes = (size_t)T_CNT * N_DST * U_DIM * sizeof(float);
    const size_t needMain = gatherBytes + NSEG_MAIN * segBytes;   // ~23 MB

    float* src_feat = (float*)d_ws;

    const int nGather = N_SRC * T_CNT;   // one thread per (src, t) slice

    if (ws_size >= needMain) {
        // Main path (always taken: ws_size is ~1.6 GB): nseg=8, eseg=32768,
        // 1024-thread scan blocks (grid 256 = 1 block/CU, 16 waves/CU),
        // XCD-partitioned by edge type.
        float* part = (float*)((char*)d_ws + gatherBytes);
        gather_kernel<<<(nGather + 255) / 256, 256, 0, stream>>>(
            input_nodes, (const float2*)node_type_emb, src_feat);
        scan_kernel<ESEG_MAIN><<<NCHUNK * T_CNT * NSEG_MAIN, 1024, 0, stream>>>(
            edge_src, edge_dst, src_feat, part);
        finalize_kernel<NSEG_MAIN><<<N_DST, 256, 0, stream>>>(
            part, output_nodes, node_emb, W, S1, S2, out);
    } else {
        // Fallback: smaller nseg, runtime loop bounds (requires pre-gather fit).
        size_t avail = (ws_size > gatherBytes) ? (ws_size - gatherBytes) : 0;
        int nseg = (int)(avail / segBytes);
        if (nseg > 32) nseg = 32;
        if (nseg < 1) nseg = 1;
        while (nseg & (nseg - 1)) nseg--;
        const int eseg = E_PER_T / nseg;
        float* part = (float*)((char*)d_ws + gatherBytes);
        gather_kernel<<<(nGather + 255) / 256, 256, 0, stream>>>(
            input_nodes, (const float2*)node_type_emb, src_feat);
        scan_kernel_gen<<<NCHUNK * T_CNT * nseg, 256, 0, stream>>>(
            edge_src, edge_dst, src_feat, part, eseg);
        switch (nseg) {
            case 32: finalize_kernel<32><<<N_DST, 256, 0, stream>>>(part, output_nodes, node_emb, W, S1, S2, out); break;
            case 16: finalize_kernel<16><<<N_DST, 256, 0, stream>>>(part, output_nodes, node_emb, W, S1, S2, out); break;
            case 8:  finalize_kernel<8><<<N_DST, 256, 0, stream>>>(part, output_nodes, node_emb, W, S1, S2, out); break;
            case 4:  finalize_kernel<4><<<N_DST, 256, 0, stream>>>(part, output_nodes, node_emb, W, S1, S2, out); break;
            case 2:  finalize_kernel<2><<<N_DST, 256, 0, stream>>>(part, output_nodes, node_emb, W, S1, S2, out); break;
            default: finalize_kernel<1><<<N_DST, 256, 0, stream>>>(part, output_nodes, node_emb, W, S1, S2, out); break;
        }
    }
}